// Round 1
// baseline (123.471 us; speedup 1.0000x reference)
//
#include <hip/hip_runtime.h>
#include <math.h>

#define B_    16
#define D_    512
#define T_    4096
#define CBN_  1024
#define CD_   8
#define NTOK_ (B_ * T_)   // 65536

// ws layout (float offsets)
#define WS_WIN_T   0                    // [512][8]  w_in transposed: [i][o]
#define WS_WOUT    4096                 // [512][8]  w_out: [o][j]
#define WS_CBN     8192                 // [1024][9] cb_n[8], c=sum(cb_n^2)
#define WS_ZE      17408                // [65536][8] z_e token-major
#define WS_IDX     (17408 + 524288)     // 541696: int[65536]
#define WS_BPART   (541696 + 65536)     // 607232: float[1024] loss partials

#define OUT_OFF_LOSS 33554432           // commitment[16], then codebook[16]
#define OUT_OFF_IDX  33554464           // indices as float [65536]

// ---------------- k0: prepare weight-normed weights + normalized codebook ----
__global__ __launch_bounds__(256) void k0_prep(const float* __restrict__ v_in,
                                               const float* __restrict__ g_in,
                                               const float* __restrict__ v_out,
                                               const float* __restrict__ g_out,
                                               const float* __restrict__ codebook,
                                               float* __restrict__ ws) {
    int bid = blockIdx.x, tid = threadIdx.x;
    if (bid < 4) {
        // normalized codebook + c
        int e = bid * 256 + tid;
        const float* c = codebook + (size_t)e * 8;
        float v[8]; float s = 0.f;
#pragma unroll
        for (int j = 0; j < 8; ++j) { v[j] = c[j]; s += v[j] * v[j]; }
        float rn = 1.0f / fmaxf(sqrtf(s), 1e-12f);
        float cs = 0.f;
        float* o = ws + WS_CBN + (size_t)e * 9;
#pragma unroll
        for (int j = 0; j < 8; ++j) { float cn = v[j] * rn; o[j] = cn; cs += cn * cn; }
        o[8] = cs;
    } else if (bid == 4) {
        // w_in_t[i][o] = g_in[o] * v_in[o][i] / ||v_in[o,:]||
        __shared__ float part[8][33];
        __shared__ float rn[8];
        int o = tid >> 5;       // 0..7
        int g = tid & 31;       // 0..31
        float s = 0.f;
        for (int i = g * 16; i < g * 16 + 16; ++i) { float x = v_in[o * 512 + i]; s += x * x; }
        part[o][g] = s;
        __syncthreads();
        if (tid < 8) {
            float t2 = 0.f;
            for (int gg = 0; gg < 32; ++gg) t2 += part[tid][gg];
            rn[tid] = g_in[tid] / sqrtf(t2);
        }
        __syncthreads();
        for (int ii = 0; ii < 2; ++ii) {
            int i = tid * 2 + ii;
#pragma unroll
            for (int oo = 0; oo < 8; ++oo)
                ws[WS_WIN_T + i * 8 + oo] = v_in[oo * 512 + i] * rn[oo];
        }
    } else {
        // w_out rows (bid 5,6): norm over 8 elems per row
        int o = (bid - 5) * 256 + tid;
        const float* vr = v_out + (size_t)o * 8;
        float v[8]; float s = 0.f;
#pragma unroll
        for (int j = 0; j < 8; ++j) { v[j] = vr[j]; s += v[j] * v[j]; }
        float rn = g_out[o] / sqrtf(s);
#pragma unroll
        for (int j = 0; j < 8; ++j) ws[WS_WOUT + o * 8 + j] = v[j] * rn;
    }
}

// ---------------- k1: in_proj -> z_e (token-major) ---------------------------
__global__ __launch_bounds__(256) void k1_inproj(const float* __restrict__ z,
                                                 const float* __restrict__ b_in,
                                                 const float* __restrict__ ws_w,
                                                 float* __restrict__ ws_ze) {
    __shared__ float w[4096];   // w_in_t [i][o]
    int tid = threadIdx.x;
#pragma unroll
    for (int k = 0; k < 4; ++k)
        ((float4*)w)[tid + k * 256] = ((const float4*)ws_w)[tid + k * 256];
    __syncthreads();

    int tok = blockIdx.x * 256 + tid;
    int b = tok >> 12;
    int t = tok & (T_ - 1);

    float4 a0, a1;
    a0.x = b_in[0]; a0.y = b_in[1]; a0.z = b_in[2]; a0.w = b_in[3];
    a1.x = b_in[4]; a1.y = b_in[5]; a1.z = b_in[6]; a1.w = b_in[7];

    const float* zp = z + (size_t)b * D_ * T_ + t;
#pragma unroll 16
    for (int i = 0; i < 512; ++i) {
        float v = zp[(size_t)i * T_];
        float4 wa = ((float4*)w)[i * 2];
        float4 wb = ((float4*)w)[i * 2 + 1];
        a0.x = fmaf(wa.x, v, a0.x); a0.y = fmaf(wa.y, v, a0.y);
        a0.z = fmaf(wa.z, v, a0.z); a0.w = fmaf(wa.w, v, a0.w);
        a1.x = fmaf(wb.x, v, a1.x); a1.y = fmaf(wb.y, v, a1.y);
        a1.z = fmaf(wb.z, v, a1.z); a1.w = fmaf(wb.w, v, a1.w);
    }
    float4* zo = (float4*)(ws_ze + (size_t)tok * 8);
    zo[0] = a0; zo[1] = a1;
}

// ---------------- k2: nearest-codebook search + loss partials ----------------
// 1024 blocks x 128 threads (2 waves). Each wave holds the FULL codebook in
// registers (16 entries/lane) and scans 32 tokens broadcast from LDS.
__global__ __launch_bounds__(128) void k2_search(const float* __restrict__ ws,
                                                 const float* __restrict__ codebook,
                                                 float* __restrict__ out_idx_f,
                                                 int* __restrict__ ws_idx,
                                                 float* __restrict__ ws_bpart) {
    __shared__ float zes[64 * 8];
    __shared__ float wl[2];
    int tid = threadIdx.x;
    int lane = tid & 63;
    int wv = tid >> 6;

    int base = blockIdx.x * 64;
    // stage 64 tokens of z_e
    ((float4*)zes)[tid] = ((const float4*)(ws + WS_ZE + (size_t)base * 8))[tid];

    // load 16 codebook entries per lane: e = k*64 + lane
    float cbn[16][8]; float cc[16];
    const float* cb = ws + WS_CBN;
#pragma unroll
    for (int k = 0; k < 16; ++k) {
        const float* p = cb + (size_t)(k * 64 + lane) * 9;
#pragma unroll
        for (int j = 0; j < 8; ++j) cbn[k][j] = p[j];
        cc[k] = p[8];
    }
    __syncthreads();

    float lossAcc = 0.f;
    for (int s = 0; s < 32; ++s) {
        int tl = wv * 32 + s;
        int tok = base + tl;
        float4 z0 = ((float4*)zes)[tl * 2];
        float4 z1 = ((float4*)zes)[tl * 2 + 1];
        float nrm2 = z0.x * z0.x + z0.y * z0.y + z0.z * z0.z + z0.w * z0.w
                   + z1.x * z1.x + z1.y * z1.y + z1.z * z1.z + z1.w * z1.w;
        float r = 1.0f / fmaxf(sqrtf(nrm2), 1e-12f);
        float e0 = z0.x * r, e1 = z0.y * r, e2 = z0.z * r, e3 = z0.w * r;
        float e4 = z1.x * r, e5 = z1.y * r, e6 = z1.z * r, e7 = z1.w * r;
        float a = e0 * e0 + e1 * e1 + e2 * e2 + e3 * e3
                + e4 * e4 + e5 * e5 + e6 * e6 + e7 * e7;

        float best = 3.4e38f; int bidx = 0x7fffffff;
#pragma unroll
        for (int k = 0; k < 16; ++k) {
            float dot = cbn[k][0] * e0;
            dot = fmaf(cbn[k][1], e1, dot);
            dot = fmaf(cbn[k][2], e2, dot);
            dot = fmaf(cbn[k][3], e3, dot);
            dot = fmaf(cbn[k][4], e4, dot);
            dot = fmaf(cbn[k][5], e5, dot);
            dot = fmaf(cbn[k][6], e6, dot);
            dot = fmaf(cbn[k][7], e7, dot);
            float dist = fmaf(dot, -2.0f, a) + cc[k];   // (a - 2*dot) + c
            int e = k * 64 + lane;
            if (dist < best) { best = dist; bidx = e; }  // ascending e -> first-min kept
        }
        // 64-lane lexicographic (dist, idx) min reduce -> all lanes converge
#pragma unroll
        for (int off = 1; off < 64; off <<= 1) {
            float ov = __shfl_xor(best, off, 64);
            int   oi = __shfl_xor(bidx, off, 64);
            if (ov < best || (ov == best && oi < bidx)) { best = ov; bidx = oi; }
        }
        // loss contribution (all lanes compute same value)
        const float4* cq = (const float4*)(codebook + (size_t)bidx * 8);
        float4 q0 = cq[0], q1 = cq[1];
        float d0 = z0.x - q0.x, d1 = z0.y - q0.y, d2 = z0.z - q0.z, d3 = z0.w - q0.w;
        float d4 = z1.x - q1.x, d5 = z1.y - q1.y, d6 = z1.z - q1.z, d7 = z1.w - q1.w;
        lossAcc += d0 * d0 + d1 * d1 + d2 * d2 + d3 * d3
                 + d4 * d4 + d5 * d5 + d6 * d6 + d7 * d7;

        if (lane == 0) {
            out_idx_f[tok] = (float)bidx;
            ws_idx[tok] = bidx;
        }
    }
    if (lane == 0) wl[wv] = lossAcc;
    __syncthreads();
    if (tid == 0) ws_bpart[blockIdx.x] = wl[0] + wl[1];
}

// ---------------- k3: out_proj + loss finalize -------------------------------
__global__ __launch_bounds__(256) void k3_outproj(const float* __restrict__ codebook,
                                                  const float* __restrict__ b_out,
                                                  const float* __restrict__ ws,
                                                  const int* __restrict__ ws_idx,
                                                  const float* __restrict__ ws_bpart,
                                                  float* __restrict__ d_out) {
    __shared__ float w[4096];   // w_out [o][j]
    __shared__ float bo[512];
    int tid = threadIdx.x;
#pragma unroll
    for (int k = 0; k < 4; ++k)
        ((float4*)w)[tid + k * 256] = ((const float4*)(ws + WS_WOUT))[tid + k * 256];
    bo[tid] = b_out[tid];
    bo[tid + 256] = b_out[tid + 256];
    __syncthreads();

    int tok = blockIdx.x * 256 + tid;
    int b = tok >> 12;
    int t = tok & (T_ - 1);
    int idx = ws_idx[tok];
    const float4* cq = (const float4*)(codebook + (size_t)idx * 8);
    float4 q0 = cq[0], q1 = cq[1];

    float* op = d_out + (size_t)b * D_ * T_ + t;
#pragma unroll 4
    for (int o = 0; o < 512; ++o) {
        float4 wa = ((float4*)w)[o * 2];
        float4 wb = ((float4*)w)[o * 2 + 1];
        float v = bo[o];
        v = fmaf(wa.x, q0.x, v); v = fmaf(wa.y, q0.y, v);
        v = fmaf(wa.z, q0.z, v); v = fmaf(wa.w, q0.w, v);
        v = fmaf(wb.x, q1.x, v); v = fmaf(wb.y, q1.y, v);
        v = fmaf(wb.z, q1.z, v); v = fmaf(wb.w, q1.w, v);
        op[(size_t)o * T_] = v;
    }

    // finalize losses (commitment == codebook numerically)
    if (blockIdx.x == 0 && tid < B_) {
        float s = 0.f;
        for (int k = 0; k < 64; ++k) s += ws_bpart[tid * 64 + k];
        float m = s * (1.0f / (CD_ * T_));
        d_out[OUT_OFF_LOSS + tid] = m;
        d_out[OUT_OFF_LOSS + 16 + tid] = m;
    }
}

// ---------------- launch -----------------------------------------------------
extern "C" void kernel_launch(void* const* d_in, const int* in_sizes, int n_in,
                              void* d_out, int out_size, void* d_ws, size_t ws_size,
                              hipStream_t stream) {
    (void)in_sizes; (void)n_in; (void)out_size; (void)ws_size;
    const float* z        = (const float*)d_in[0];
    const float* v_in     = (const float*)d_in[1];
    const float* g_in     = (const float*)d_in[2];
    const float* b_in     = (const float*)d_in[3];
    const float* v_out    = (const float*)d_in[4];
    const float* g_out    = (const float*)d_in[5];
    const float* b_out    = (const float*)d_in[6];
    const float* codebook = (const float*)d_in[7];
    float* ws  = (float*)d_ws;
    float* out = (float*)d_out;

    hipLaunchKernelGGL(k0_prep, dim3(7), dim3(256), 0, stream,
                       v_in, g_in, v_out, g_out, codebook, ws);
    hipLaunchKernelGGL(k1_inproj, dim3(NTOK_ / 256), dim3(256), 0, stream,
                       z, b_in, ws + WS_WIN_T, ws + WS_ZE);
    hipLaunchKernelGGL(k2_search, dim3(NTOK_ / 64), dim3(128), 0, stream,
                       ws, codebook, out + OUT_OFF_IDX,
                       (int*)(ws + WS_IDX), ws + WS_BPART);
    hipLaunchKernelGGL(k3_outproj, dim3(NTOK_ / 256), dim3(256), 0, stream,
                       codebook, b_out, ws, (const int*)(ws + WS_IDX),
                       ws + WS_BPART, out);
}

// Round 2
// 109.190 us; speedup vs baseline: 1.1308x; 1.1308x over previous
//
#include <hip/hip_runtime.h>
#include <math.h>

#define B_    16
#define D_    512
#define T_    4096
#define CBN_  1024
#define CD_   8
#define NTOK_ (B_ * T_)   // 65536

// ws layout (float offsets)
#define WS_WIN_T   0                        // [512][8]  w_in transposed: [i][o]
#define WS_WOUT    4096                     // [512][8]  w_out: [o][j]
#define WS_CBN     8192                     // [1024][9] cb_n[8], c=sum(cb_n^2)
#define WS_ZEP     17408                    // [8][65536][8] z_e partials (chunk-major)
#define WS_IDX     (17408 + 4194304)        // 4211712: int[65536]
#define WS_BPART   (4211712 + 65536)        // 4277248: float[1024] loss partials

#define OUT_OFF_LOSS 33554432               // commitment[16], then codebook[16]
#define OUT_OFF_IDX  33554464               // indices as float [65536]

// ---------------- k0: prepare weight-normed weights + normalized codebook ----
__global__ __launch_bounds__(256) void k0_prep(const float* __restrict__ v_in,
                                               const float* __restrict__ g_in,
                                               const float* __restrict__ v_out,
                                               const float* __restrict__ g_out,
                                               const float* __restrict__ codebook,
                                               float* __restrict__ ws) {
    int bid = blockIdx.x, tid = threadIdx.x;
    if (bid < 4) {
        // normalized codebook + c
        int e = bid * 256 + tid;
        const float* c = codebook + (size_t)e * 8;
        float v[8]; float s = 0.f;
#pragma unroll
        for (int j = 0; j < 8; ++j) { v[j] = c[j]; s += v[j] * v[j]; }
        float rn = 1.0f / fmaxf(sqrtf(s), 1e-12f);
        float cs = 0.f;
        float* o = ws + WS_CBN + (size_t)e * 9;
#pragma unroll
        for (int j = 0; j < 8; ++j) { float cn = v[j] * rn; o[j] = cn; cs += cn * cn; }
        o[8] = cs;
    } else if (bid == 4) {
        // w_in_t[i][o] = g_in[o] * v_in[o][i] / ||v_in[o,:]||
        __shared__ float part[8][33];
        __shared__ float rn[8];
        int o = tid >> 5;       // 0..7
        int g = tid & 31;       // 0..31
        float s = 0.f;
        for (int i = g * 16; i < g * 16 + 16; ++i) { float x = v_in[o * 512 + i]; s += x * x; }
        part[o][g] = s;
        __syncthreads();
        if (tid < 8) {
            float t2 = 0.f;
            for (int gg = 0; gg < 32; ++gg) t2 += part[tid][gg];
            rn[tid] = g_in[tid] / sqrtf(t2);
        }
        __syncthreads();
        for (int ii = 0; ii < 2; ++ii) {
            int i = tid * 2 + ii;
#pragma unroll
            for (int oo = 0; oo < 8; ++oo)
                ws[WS_WIN_T + i * 8 + oo] = v_in[oo * 512 + i] * rn[oo];
        }
    } else {
        // w_out rows (bid 5,6): norm over 8 elems per row
        int o = (bid - 5) * 256 + tid;
        const float* vr = v_out + (size_t)o * 8;
        float v[8]; float s = 0.f;
#pragma unroll
        for (int j = 0; j < 8; ++j) { v[j] = vr[j]; s += v[j] * v[j]; }
        float rn = g_out[o] / sqrtf(s);
#pragma unroll
        for (int j = 0; j < 8; ++j) ws[WS_WOUT + o * 8 + j] = v[j] * rn;
    }
}

// ---------------- k1: in_proj partials over D-chunks -------------------------
// grid (256, 8): blockIdx.x = token block (256 tokens), blockIdx.y = D-chunk
// (64 rows). Each thread accumulates an 8-dim partial for one token.
__global__ __launch_bounds__(256) void k1_inproj(const float* __restrict__ z,
                                                 const float* __restrict__ ws_w,
                                                 float* __restrict__ ws_zep) {
    __shared__ float w[512];   // w_in_t chunk [64][8]
    int tid = threadIdx.x;
    int c = blockIdx.y;
    if (tid < 128)
        ((float4*)w)[tid] = ((const float4*)(ws_w + c * 512))[tid];
    __syncthreads();

    int tok = blockIdx.x * 256 + tid;
    int b = tok >> 12;
    int t = tok & (T_ - 1);

    float4 a0 = make_float4(0.f, 0.f, 0.f, 0.f);
    float4 a1 = make_float4(0.f, 0.f, 0.f, 0.f);

    const float* zp = z + (size_t)b * D_ * T_ + (size_t)(c * 64) * T_ + t;
#pragma unroll 8
    for (int i = 0; i < 64; ++i) {
        float v = zp[(size_t)i * T_];
        float4 wa = ((float4*)w)[i * 2];
        float4 wb = ((float4*)w)[i * 2 + 1];
        a0.x = fmaf(wa.x, v, a0.x); a0.y = fmaf(wa.y, v, a0.y);
        a0.z = fmaf(wa.z, v, a0.z); a0.w = fmaf(wa.w, v, a0.w);
        a1.x = fmaf(wb.x, v, a1.x); a1.y = fmaf(wb.y, v, a1.y);
        a1.z = fmaf(wb.z, v, a1.z); a1.w = fmaf(wb.w, v, a1.w);
    }
    float4* zo = (float4*)(ws_zep + ((size_t)c * NTOK_ + tok) * 8);
    zo[0] = a0; zo[1] = a1;
}

// ---------------- k2: partial-reduce + nearest-codebook search ---------------
// 1024 blocks x 128 threads (2 waves). Each wave holds the FULL codebook in
// registers (16 entries/lane) and scans 32 tokens broadcast from LDS.
__global__ __launch_bounds__(128) void k2_search(const float* __restrict__ ws,
                                                 const float* __restrict__ b_in,
                                                 const float* __restrict__ codebook,
                                                 float* __restrict__ out_idx_f,
                                                 int* __restrict__ ws_idx,
                                                 float* __restrict__ ws_bpart) {
    __shared__ float zes[64 * 8];
    __shared__ float wl[2];
    int tid = threadIdx.x;
    int lane = tid & 63;
    int wv = tid >> 6;

    int base = blockIdx.x * 64;
    // stage 64 tokens of z_e = sum of 8 chunk-partials + bias
    {
        float4 bia = ((const float4*)b_in)[tid & 1];
        const float4* zp = (const float4*)(ws + WS_ZEP);
        size_t o = (size_t)base * 2 + tid;
        float4 s = bia;
#pragma unroll
        for (int c = 0; c < 8; ++c) {
            float4 v = zp[(size_t)c * (NTOK_ * 2) + o];
            s.x += v.x; s.y += v.y; s.z += v.z; s.w += v.w;
        }
        ((float4*)zes)[tid] = s;
    }

    // load 16 codebook entries per lane: e = k*64 + lane
    float cbn[16][8]; float cc[16];
    const float* cb = ws + WS_CBN;
#pragma unroll
    for (int k = 0; k < 16; ++k) {
        const float* p = cb + (size_t)(k * 64 + lane) * 9;
#pragma unroll
        for (int j = 0; j < 8; ++j) cbn[k][j] = p[j];
        cc[k] = p[8];
    }
    __syncthreads();

    float lossAcc = 0.f;
    for (int s = 0; s < 32; ++s) {
        int tl = wv * 32 + s;
        int tok = base + tl;
        float4 z0 = ((float4*)zes)[tl * 2];
        float4 z1 = ((float4*)zes)[tl * 2 + 1];
        float nrm2 = z0.x * z0.x + z0.y * z0.y + z0.z * z0.z + z0.w * z0.w
                   + z1.x * z1.x + z1.y * z1.y + z1.z * z1.z + z1.w * z1.w;
        float r = 1.0f / fmaxf(sqrtf(nrm2), 1e-12f);
        float e0 = z0.x * r, e1 = z0.y * r, e2 = z0.z * r, e3 = z0.w * r;
        float e4 = z1.x * r, e5 = z1.y * r, e6 = z1.z * r, e7 = z1.w * r;
        float a = e0 * e0 + e1 * e1 + e2 * e2 + e3 * e3
                + e4 * e4 + e5 * e5 + e6 * e6 + e7 * e7;

        float best = 3.4e38f; int bidx = 0x7fffffff;
#pragma unroll
        for (int k = 0; k < 16; ++k) {
            float dot = cbn[k][0] * e0;
            dot = fmaf(cbn[k][1], e1, dot);
            dot = fmaf(cbn[k][2], e2, dot);
            dot = fmaf(cbn[k][3], e3, dot);
            dot = fmaf(cbn[k][4], e4, dot);
            dot = fmaf(cbn[k][5], e5, dot);
            dot = fmaf(cbn[k][6], e6, dot);
            dot = fmaf(cbn[k][7], e7, dot);
            float dist = fmaf(dot, -2.0f, a) + cc[k];   // (a - 2*dot) + c
            int e = k * 64 + lane;
            if (dist < best) { best = dist; bidx = e; }  // ascending e -> first-min kept
        }
        // 64-lane lexicographic (dist, idx) min reduce -> all lanes converge
#pragma unroll
        for (int off = 1; off < 64; off <<= 1) {
            float ov = __shfl_xor(best, off, 64);
            int   oi = __shfl_xor(bidx, off, 64);
            if (ov < best || (ov == best && oi < bidx)) { best = ov; bidx = oi; }
        }
        // loss contribution (all lanes compute same value)
        const float4* cq = (const float4*)(codebook + (size_t)bidx * 8);
        float4 q0 = cq[0], q1 = cq[1];
        float d0 = z0.x - q0.x, d1 = z0.y - q0.y, d2 = z0.z - q0.z, d3 = z0.w - q0.w;
        float d4 = z1.x - q1.x, d5 = z1.y - q1.y, d6 = z1.z - q1.z, d7 = z1.w - q1.w;
        lossAcc += d0 * d0 + d1 * d1 + d2 * d2 + d3 * d3
                 + d4 * d4 + d5 * d5 + d6 * d6 + d7 * d7;

        if (lane == 0) {
            out_idx_f[tok] = (float)bidx;
            ws_idx[tok] = bidx;
        }
    }
    if (lane == 0) wl[wv] = lossAcc;
    __syncthreads();
    if (tid == 0) ws_bpart[blockIdx.x] = wl[0] + wl[1];
}

// ---------------- k3: out_proj over D-chunks + loss finalize -----------------
// grid (256, 8): blockIdx.x = token block (256 tokens), blockIdx.y = out-chunk
// (64 rows). Each thread writes 64 output rows for one token.
__global__ __launch_bounds__(256) void k3_outproj(const float* __restrict__ codebook,
                                                  const float* __restrict__ b_out,
                                                  const float* __restrict__ ws,
                                                  const int* __restrict__ ws_idx,
                                                  const float* __restrict__ ws_bpart,
                                                  float* __restrict__ d_out) {
    __shared__ float w[512];   // w_out chunk [64][8]
    __shared__ float bo[64];
    int tid = threadIdx.x;
    int c = blockIdx.y;
    if (tid < 128)
        ((float4*)w)[tid] = ((const float4*)(ws + WS_WOUT + c * 512))[tid];
    if (tid < 64) bo[tid] = b_out[c * 64 + tid];
    __syncthreads();

    int tok = blockIdx.x * 256 + tid;
    int b = tok >> 12;
    int t = tok & (T_ - 1);
    int idx = ws_idx[tok];
    const float4* cq = (const float4*)(codebook + (size_t)idx * 8);
    float4 q0 = cq[0], q1 = cq[1];

    float* op = d_out + (size_t)b * D_ * T_ + (size_t)(c * 64) * T_ + t;
#pragma unroll 8
    for (int o = 0; o < 64; ++o) {
        float4 wa = ((float4*)w)[o * 2];
        float4 wb = ((float4*)w)[o * 2 + 1];
        float v = bo[o];
        v = fmaf(wa.x, q0.x, v); v = fmaf(wa.y, q0.y, v);
        v = fmaf(wa.z, q0.z, v); v = fmaf(wa.w, q0.w, v);
        v = fmaf(wb.x, q1.x, v); v = fmaf(wb.y, q1.y, v);
        v = fmaf(wb.z, q1.z, v); v = fmaf(wb.w, q1.w, v);
        op[(size_t)o * T_] = v;
    }

    // finalize losses (commitment == codebook numerically)
    if (blockIdx.x == 0 && c == 0 && tid < B_) {
        float s = 0.f;
        for (int k = 0; k < 64; ++k) s += ws_bpart[tid * 64 + k];
        float m = s * (1.0f / (CD_ * T_));
        d_out[OUT_OFF_LOSS + tid] = m;
        d_out[OUT_OFF_LOSS + 16 + tid] = m;
    }
}

// ---------------- launch -----------------------------------------------------
extern "C" void kernel_launch(void* const* d_in, const int* in_sizes, int n_in,
                              void* d_out, int out_size, void* d_ws, size_t ws_size,
                              hipStream_t stream) {
    (void)in_sizes; (void)n_in; (void)out_size; (void)ws_size;
    const float* z        = (const float*)d_in[0];
    const float* v_in     = (const float*)d_in[1];
    const float* g_in     = (const float*)d_in[2];
    const float* b_in     = (const float*)d_in[3];
    const float* v_out    = (const float*)d_in[4];
    const float* g_out    = (const float*)d_in[5];
    const float* b_out    = (const float*)d_in[6];
    const float* codebook = (const float*)d_in[7];
    float* ws  = (float*)d_ws;
    float* out = (float*)d_out;

    hipLaunchKernelGGL(k0_prep, dim3(7), dim3(256), 0, stream,
                       v_in, g_in, v_out, g_out, codebook, ws);
    hipLaunchKernelGGL(k1_inproj, dim3(NTOK_ / 256, 8), dim3(256), 0, stream,
                       z, ws + WS_WIN_T, ws + WS_ZEP);
    hipLaunchKernelGGL(k2_search, dim3(NTOK_ / 64), dim3(128), 0, stream,
                       ws, b_in, codebook, out + OUT_OFF_IDX,
                       (int*)(ws + WS_IDX), ws + WS_BPART);
    hipLaunchKernelGGL(k3_outproj, dim3(NTOK_ / 256, 8), dim3(256), 0, stream,
                       codebook, b_out, ws, (const int*)(ws + WS_IDX),
                       ws + WS_BPART, out);
}